// Round 5
// baseline (1357.593 us; speedup 1.0000x reference)
//
#include <hip/hip_runtime.h>

#define XS    256
#define XS2   65536
#define LAT   10

// Native fire-and-forget f32 atomic (global_atomic_add_f32 on gfx950).
// Plain atomicAdd(float*) on GLOBAL memory lowers to a CAS retry loop
// (round-1: 780 MB WRITE_SIZE, 1220 us). unsafeAtomicAdd emits the native
// no-return add which resolves at the LLC coherence point.
__device__ __forceinline__ void fadd_atomic(float* p, float v) {
    unsafeAtomicAdd(p, v);
}

// ---------------------------------------------------------------------------
// Coordinate math (matches reference: fmaf-pinned).
// ---------------------------------------------------------------------------
__device__ __forceinline__ void compute_rc(const float* __restrict__ flow,
                                           const int* __restrict__ inds,
                                           const float* __restrict__ rot,
                                           const float* __restrict__ shifts,
                                           int b, int n, int N,
                                           int& r, int& c, float& f0, float& f1) {
    const float* R = rot + b * 9;
    float r00 = R[0], r01 = R[1], r02 = R[2];
    float r10 = R[3], r11 = R[4], r12 = R[5];
    float s0 = shifts[b * 2 + 0], s1 = shifts[b * 2 + 1];
    size_t fo = ((size_t)b * N + n) * 3;
    float fw0 = flow[fo + 0], fw1 = flow[fo + 1], fw2 = flow[fo + 2];
    float v0 = (float)inds[n * 3 + 2] - 128.0f + fw0;
    float v1 = (float)inds[n * 3 + 1] - 128.0f + fw1;
    float v2 = (float)inds[n * 3 + 0] - 128.0f + fw2;
    float p0 = fmaf(v0, r00, fmaf(v1, r01, fmaf(v2, r02, 128.0f - s0)));
    float p1 = fmaf(v0, r10, fmaf(v1, r11, fmaf(v2, r12, 128.0f - s1)));
    float cs0 = p1, cs1 = p0;     // c_sampling = (coords[...,1], coords[...,0])
    float ff0 = floorf(cs0), ff1 = floorf(cs1);
    r = (int)ff0; c = (int)ff1;
    f0 = cs0 - ff0; f1 = cs1 - ff1;
}

// JAX .at[].add semantics: negative indices wrap once, then OOB dropped.
__device__ __forceinline__ void corner_atomic(float* I, int rr, int cc, float a) {
    if (rr >= -XS && rr < XS && cc >= -XS && cc < XS)
        fadd_atomic(I + ((rr + XS) & (XS - 1)) * XS + ((cc + XS) & (XS - 1)), a);
}

// ---------------------------------------------------------------------------
// Direct bilinear scatter with native global atomics (no sort, no LDS).
// ---------------------------------------------------------------------------
__global__ void __launch_bounds__(256)
scatter_kernel(const float* __restrict__ flow,
               const float* __restrict__ values,
               const int* __restrict__ inds,
               const float* __restrict__ rot,
               const float* __restrict__ shifts,
               float* __restrict__ img, int N) {
    int b = blockIdx.y;
    int n = blockIdx.x * blockDim.x + threadIdx.x;
    if (n >= N) return;
    int r, c; float f0, f1;
    compute_rc(flow, inds, rot, shifts, b, n, N, r, c, f0, f1);
    float amp = values[n];
    float g0 = 1.0f - f0, g1 = 1.0f - f1;
    float a0 = amp * g0 * g1;   // (r,   c)
    float a1 = amp * f0 * g1;   // (r+1, c)
    float a2 = amp * f0 * f1;   // (r+1, c+1)
    float a3 = amp * g0 * f1;   // (r,   c+1)
    float* I = img + (size_t)b * XS2;
    corner_atomic(I, r,     c,     a0);
    corner_atomic(I, r + 1, c,     a1);
    corner_atomic(I, r + 1, c + 1, a2);
    corner_atomic(I, r,     c + 1, a3);
}

// ---------------------------------------------------------------------------
// MLP split-K partials: h_raw[b,l] = sum_e x[b,e]*w1[e,l]
// ---------------------------------------------------------------------------
__global__ void mlp_partial(const float* __restrict__ x,
                            const float* __restrict__ w1,
                            float* __restrict__ hraw, int B) {
    int base = blockIdx.x * 256;
    int t = threadIdx.x;
    if (t >= B * LAT) return;
    int b = t / LAT, l = t - b * LAT;
    const float* xb = x + (size_t)b * XS2 + base;
    const float* w  = w1 + (size_t)base * LAT + l;
    float acc = 0.0f;
#pragma unroll 8
    for (int e = 0; e < 256; e++) acc += xb[e] * w[e * LAT];
    fadd_atomic(&hraw[b * LAT + l], acc);
}

// ---------------------------------------------------------------------------
// Separable 3x3 blur (zero-pad SAME) + per-batch affine from MLP.
// ---------------------------------------------------------------------------
__global__ void blur_kernel(const float* __restrict__ img,
                            const float* __restrict__ hraw,
                            const float* __restrict__ b1,
                            const float* __restrict__ w2,
                            const float* __restrict__ b2,
                            float* __restrict__ out) {
    int b = blockIdx.y, r = blockIdx.x, c = threadIdx.x;
    float av = b2[0], bv = b2[1];
#pragma unroll
    for (int l = 0; l < LAT; l++) {
        float h = hraw[b * LAT + l] + b1[l];
        h = h > 0.0f ? h : 0.0f;
        av += h * w2[l * 2 + 0];
        bv += h * w2[l * 2 + 1];
    }
    const float g   = 0.6065306597126334f;   // exp(-0.5)
    const float inv = 1.0f / (1.0f + 2.0f * g);
    const float* I = img + (size_t)b * XS2;
    float up  = (r > 0)      ? I[(r - 1) * XS + c] : 0.0f;
    float mid =                I[r * XS + c];
    float dn  = (r < XS - 1) ? I[(r + 1) * XS + c] : 0.0f;
    float v = (g * (up + dn) + mid) * inv;
    __shared__ float row[XS + 2];
    row[c + 1] = v;
    if (c == 0) { row[0] = 0.0f; row[XS + 1] = 0.0f; }
    __syncthreads();
    float hh = (g * (row[c] + row[c + 2]) + v) * inv;
    out[(size_t)b * XS2 + (size_t)r * XS + c] = av * hh + bv;
}

extern "C" void kernel_launch(void* const* d_in, const int* in_sizes, int n_in,
                              void* d_out, int out_size, void* d_ws, size_t ws_size,
                              hipStream_t stream) {
    const float* flow   = (const float*)d_in[0];
    const float* x      = (const float*)d_in[1];
    const float* values = (const float*)d_in[2];
    const float* rot    = (const float*)d_in[3];
    const float* shifts = (const float*)d_in[4];
    const float* w1     = (const float*)d_in[5];
    const float* b1     = (const float*)d_in[6];
    const float* w2     = (const float*)d_in[7];
    const float* b2     = (const float*)d_in[8];
    const int*   inds   = (const int*)d_in[9];

    int N = in_sizes[2];          // values: (N,)
    int B = in_sizes[4] / 2;      // shifts: (B,2)

    float* img  = (float*)d_ws;                 // B*256*256 f32 accumulator
    float* hraw = img + (size_t)B * XS2;        // B*LAT f32 MLP partials

    hipMemsetAsync(d_ws, 0, ((size_t)B * XS2 + 256) * sizeof(float), stream);

    dim3 g1((N + 255) / 256, B);
    scatter_kernel<<<g1, 256, 0, stream>>>(flow, values, inds, rot, shifts, img, N);

    mlp_partial<<<XS2 / 256, 256, 0, stream>>>(x, w1, hraw, B);

    dim3 g3(XS, B);
    blur_kernel<<<g3, XS, 0, stream>>>(img, hraw, b1, w2, b2, (float*)d_out);
}

// Round 6
// 235.333 us; speedup vs baseline: 5.7688x; 5.7688x over previous
//
#include <hip/hip_runtime.h>

#define XS     256
#define XS2    65536
#define LAT    10
#define BR     8             // rows per bin group
#define NG     (XS / BR)     // 32 groups per image
#define NBINS  512           // B(16) * NG(32)
#define P1     2048          // blocks for place pass
#define K_MAX  16            // max items per thread in place
#define SPLIT  2             // accum sub-blocks per bin
#define BINCAP 15360         // per-bin record capacity (mean ~12.4k)
#define FSCALE 262144.0f     // 2^18 fixed-point scale

// Native no-return f32 global atomic (global_atomic_add_f32).
__device__ __forceinline__ void fadd_atomic(float* p, float v) {
    unsafeAtomicAdd(p, v);
}

// ---------------------------------------------------------------------------
// Coordinate math (fmaf-pinned; shared by all paths).
// ---------------------------------------------------------------------------
__device__ __forceinline__ void compute_rc(const float* __restrict__ flow,
                                           const int* __restrict__ inds,
                                           const float* __restrict__ rot,
                                           const float* __restrict__ shifts,
                                           int b, int n, int N,
                                           int& r, int& c, float& f0, float& f1) {
    const float* R = rot + b * 9;
    float r00 = R[0], r01 = R[1], r02 = R[2];
    float r10 = R[3], r11 = R[4], r12 = R[5];
    float s0 = shifts[b * 2 + 0], s1 = shifts[b * 2 + 1];
    size_t fo = ((size_t)b * N + n) * 3;
    float fw0 = flow[fo + 0], fw1 = flow[fo + 1], fw2 = flow[fo + 2];
    float v0 = (float)inds[n * 3 + 2] - 128.0f + fw0;
    float v1 = (float)inds[n * 3 + 1] - 128.0f + fw1;
    float v2 = (float)inds[n * 3 + 0] - 128.0f + fw2;
    float p0 = fmaf(v0, r00, fmaf(v1, r01, fmaf(v2, r02, 128.0f - s0)));
    float p1 = fmaf(v0, r10, fmaf(v1, r11, fmaf(v2, r12, 128.0f - s1)));
    float cs0 = p1, cs1 = p0;     // c_sampling = (coords[...,1], coords[...,0])
    float ff0 = floorf(cs0), ff1 = floorf(cs1);
    r = (int)ff0; c = (int)ff1;
    f0 = cs0 - ff0; f1 = cs1 - ff1;
}

// JAX .at[].add semantics: negative indices wrap once, then OOB dropped.
__device__ __forceinline__ void corner_atomic(float* I, int rr, int cc, float a) {
    if (rr >= -XS && rr < XS && cc >= -XS && cc < XS)
        fadd_atomic(I + ((rr + XS) & (XS - 1)) * XS + ((cc + XS) & (XS - 1)), a);
}

// fast path iff rows r, r+1 both valid and don't wrap-split.
__device__ __forceinline__ bool is_fast(int r) {
    return (r >= -XS) && (r <= XS - 2) && (r != -1);
}

// Record: low word = rig[0:2] wc[3:10] cv0[11] cv1[12] q0[13:21] q1[22:30];
// high word = amp f32 bits.
__device__ __forceinline__ void rec_fallback(unsigned long long rec, int bin,
                                             float* __restrict__ img) {
    unsigned w = (unsigned)rec;
    float amp = __uint_as_float((unsigned)(rec >> 32));
    int b = bin >> 5, g = bin & 31;
    int rig = w & 7, wc = (w >> 3) & 255;
    int wr = g * BR + rig;
    float f0 = (float)((w >> 13) & 511) * (1.0f / 512.0f);
    float f1 = (float)((w >> 22) & 511) * (1.0f / 512.0f);
    float g0 = 1.0f - f0, g1 = 1.0f - f1;
    float* I = img + (size_t)b * XS2;
    if (w & (1u << 11)) {
        fadd_atomic(&I[wr * XS + wc],       amp * g0 * g1);
        fadd_atomic(&I[(wr + 1) * XS + wc], amp * f0 * g1);
    }
    if (w & (1u << 12)) {
        int wc1 = (wc + 1) & 255;
        fadd_atomic(&I[wr * XS + wc1],       amp * g0 * f1);
        fadd_atomic(&I[(wr + 1) * XS + wc1], amp * f0 * f1);
    }
}

// ---------------------------------------------------------------------------
// Pass 1 (fused hist+place): one LDS rtn-atomic per item gives in-block rank;
// one global cursor atomic per (bin,block) reserves contiguous space in the
// bin's fixed-capacity region. Slow/overflow records -> direct global atomics.
// ---------------------------------------------------------------------------
__global__ void __launch_bounds__(256)
place_direct(const float* __restrict__ flow,
             const float* __restrict__ values,
             const int* __restrict__ inds,
             const float* __restrict__ rot,
             const float* __restrict__ shifts,
             unsigned* __restrict__ gcursor,
             unsigned long long* __restrict__ recs,
             float* __restrict__ img,
             int N, int TI, int IPB) {
    __shared__ unsigned lcnt[NBINS];
    __shared__ unsigned lbase[NBINS];
    int t = threadIdx.x;
    lcnt[t] = 0; lcnt[t + 256] = 0;
    __syncthreads();

    unsigned long long rec[K_MAX];
    unsigned meta[K_MAX];        // bin | rank<<9 ; 0xFFFFFFFF = none
    int s = blockIdx.x * IPB;
    int e = min(s + IPB, TI);

#pragma unroll
    for (int k = 0; k < K_MAX; k++) {
        meta[k] = 0xFFFFFFFFu;
        int i = s + t + k * 256;
        if (i < e) {
            int b = i / N, n = i - b * N;
            int r, c; float f0, f1;
            compute_rc(flow, inds, rot, shifts, b, n, N, r, c, f0, f1);
            float amp = values[n];
            if (is_fast(r)) {
                int wr = (r + XS) & (XS - 1);
                int wc = c & (XS - 1);
                unsigned cv0 = (c >= -XS && c < XS) ? 1u : 0u;
                unsigned cv1 = (c + 1 >= -XS && c + 1 < XS) ? 1u : 0u;
                unsigned q0 = min(511u, (unsigned)(f0 * 512.0f + 0.5f));
                unsigned q1 = min(511u, (unsigned)(f1 * 512.0f + 0.5f));
                unsigned word = (unsigned)(wr & 7) | ((unsigned)wc << 3) |
                                (cv0 << 11) | (cv1 << 12) | (q0 << 13) | (q1 << 22);
                int bin = b * NG + (wr >> 3);
                unsigned rank = atomicAdd(&lcnt[bin], 1u);
                meta[k] = (unsigned)bin | (rank << 9);
                rec[k] = ((unsigned long long)__float_as_uint(amp) << 32) | word;
            } else {
                float g0 = 1.0f - f0, g1 = 1.0f - f1;
                float* I = img + (size_t)b * XS2;
                corner_atomic(I, r,     c,     amp * g0 * g1);
                corner_atomic(I, r + 1, c,     amp * f0 * g1);
                corner_atomic(I, r + 1, c + 1, amp * f0 * f1);
                corner_atomic(I, r,     c + 1, amp * g0 * f1);
            }
        }
    }
    __syncthreads();

    // reserve global space per touched bin
    for (int bin = t; bin < NBINS; bin += 256) {
        unsigned cn = lcnt[bin];
        lbase[bin] = cn ? atomicAdd(&gcursor[bin], cn) : 0u;
    }
    __syncthreads();

#pragma unroll
    for (int k = 0; k < K_MAX; k++) {
        unsigned m = meta[k];
        if (m != 0xFFFFFFFFu) {
            unsigned bin = m & (NBINS - 1);
            unsigned idx = lbase[bin] + (m >> 9);
            if (idx < BINCAP) recs[(size_t)bin * BINCAP + idx] = rec[k];
            else rec_fallback(rec[k], (int)bin, img);   // capacity overflow (rare)
        }
    }
}

// ---------------------------------------------------------------------------
// Pass 2: u64 fixed-point LDS accumulation. Cell[rig][col]: lo32 = row rig,
// hi32 = row rig+1 contributions (signed, exact in mod-2^64). 2 atomics/rec.
// ---------------------------------------------------------------------------
__global__ void __launch_bounds__(256)
accum_u64(const unsigned long long* __restrict__ recs,
          const unsigned* __restrict__ gcursor,
          float* __restrict__ reps,
          float* __restrict__ aprons, int B) {
    int bin = blockIdx.x / SPLIT, sp = blockIdx.x - bin * SPLIT;
    int b = bin >> 5, g = bin & 31;
    __shared__ unsigned long long tile[BR * XS];   // 16 KB
    int t = threadIdx.x;
    for (int k = t; k < BR * XS; k += 256) tile[k] = 0ull;
    __syncthreads();

    unsigned cnt = min(gcursor[bin], (unsigned)BINCAP);
    unsigned lo = (unsigned)(((unsigned long long)cnt * sp) / SPLIT);
    unsigned hi = (unsigned)(((unsigned long long)cnt * (sp + 1)) / SPLIT);
    const unsigned long long* rb = recs + (size_t)bin * BINCAP;

    for (unsigned i = lo + t; i < hi; i += 256) {
        unsigned long long rc = rb[i];
        unsigned w = (unsigned)rc;
        float amp = __uint_as_float((unsigned)(rc >> 32));
        int rig = w & 7, wc = (w >> 3) & 255;
        float f0 = (float)((w >> 13) & 511) * (1.0f / 512.0f);
        float f1 = (float)((w >> 22) & 511) * (1.0f / 512.0f);
        float g0 = 1.0f - f0, g1 = 1.0f - f1;
        int base = rig * XS;
        if (w & (1u << 11)) {
            float cl = amp * g1;
            int qlo = __float2int_rn(cl * g0 * FSCALE);
            int qhi = __float2int_rn(cl * f0 * FSCALE);
            unsigned long long inc =
                (unsigned long long)(((long long)qhi << 32) + (long long)qlo);
            __hip_atomic_fetch_add(&tile[base + wc], inc,
                                   __ATOMIC_RELAXED, __HIP_MEMORY_SCOPE_WORKGROUP);
        }
        if (w & (1u << 12)) {
            float cr = amp * f1;
            int qlo = __float2int_rn(cr * g0 * FSCALE);
            int qhi = __float2int_rn(cr * f0 * FSCALE);
            unsigned long long inc =
                (unsigned long long)(((long long)qhi << 32) + (long long)qlo);
            __hip_atomic_fetch_add(&tile[base + ((wc + 1) & (XS - 1))], inc,
                                   __ATOMIC_RELAXED, __HIP_MEMORY_SCOPE_WORKGROUP);
        }
    }
    __syncthreads();

    // flush: row r total = lo(cell[r]) + hi(cell[r-1]); row 8 = apron.
    const float invS = 1.0f / FSCALE;
    float* rep = reps + ((size_t)sp * B + b) * XS2;
    for (int k = t; k < (BR + 1) * XS; k += 256) {
        int row = k >> 8, col = k & 255;
        long long acc = 0;
        if (row < BR) {
            unsigned long long s0 = tile[row * XS + col];
            acc += (long long)(int)(unsigned)(s0 & 0xffffffffull);
        }
        if (row >= 1) {
            unsigned long long s1 = tile[(row - 1) * XS + col];
            long long lo32 = (long long)(int)(unsigned)(s1 & 0xffffffffull);
            acc += ((long long)s1 - lo32) >> 32;
        }
        float v = (float)acc * invS;
        if (row < BR) rep[(g * BR + row) * XS + col] = v;
        else          aprons[((size_t)bin * SPLIT + sp) * XS + col] = v;
    }
}

// ---------------------------------------------------------------------------
// Pass 3: img += sum of replicas (+ aprons at r = 8k).
// ---------------------------------------------------------------------------
__global__ void combine_kernel(float* __restrict__ img,
                               const float* __restrict__ reps,
                               const float* __restrict__ aprons, int B) {
    int b = blockIdx.y, r = blockIdx.x, c = threadIdx.x;
    size_t off = (size_t)b * XS2 + r * XS + c;
    float v = img[off];
#pragma unroll
    for (int sp = 0; sp < SPLIT; sp++)
        v += reps[((size_t)sp * B + b) * XS2 + r * XS + c];
    if (r >= BR && (r & (BR - 1)) == 0) {
        int g = (r >> 3) - 1;
        int bin = b * NG + g;
#pragma unroll
        for (int sp = 0; sp < SPLIT; sp++)
            v += aprons[((size_t)bin * SPLIT + sp) * XS + c];
    }
    img[off] = v;
}

// ---------------------------------------------------------------------------
// Fallback direct-scatter (tiny ws / unexpected shapes).
// ---------------------------------------------------------------------------
__global__ void scatter_kernel(const float* __restrict__ flow,
                               const float* __restrict__ values,
                               const int* __restrict__ inds,
                               const float* __restrict__ rot,
                               const float* __restrict__ shifts,
                               float* __restrict__ img, int N) {
    int b = blockIdx.y;
    int n = blockIdx.x * blockDim.x + threadIdx.x;
    if (n >= N) return;
    int r, c; float f0, f1;
    compute_rc(flow, inds, rot, shifts, b, n, N, r, c, f0, f1);
    float amp = values[n];
    float g0 = 1.0f - f0, g1 = 1.0f - f1;
    float* I = img + (size_t)b * XS2;
    corner_atomic(I, r,     c,     amp * g0 * g1);
    corner_atomic(I, r + 1, c,     amp * f0 * g1);
    corner_atomic(I, r + 1, c + 1, amp * f0 * f1);
    corner_atomic(I, r,     c + 1, amp * g0 * f1);
}

// ---------------------------------------------------------------------------
// MLP split-K partials.
// ---------------------------------------------------------------------------
__global__ void mlp_partial(const float* __restrict__ x,
                            const float* __restrict__ w1,
                            float* __restrict__ hraw, int B) {
    int base = blockIdx.x * 256;
    int t = threadIdx.x;
    if (t >= B * LAT) return;
    int b = t / LAT, l = t - b * LAT;
    const float* xb = x + (size_t)b * XS2 + base;
    const float* w  = w1 + (size_t)base * LAT + l;
    float acc = 0.0f;
#pragma unroll 8
    for (int e = 0; e < 256; e++) acc += xb[e] * w[e * LAT];
    fadd_atomic(&hraw[b * LAT + l], acc);
}

// ---------------------------------------------------------------------------
// Separable 3x3 blur (zero-pad SAME) + per-batch affine.
// ---------------------------------------------------------------------------
__global__ void blur_kernel(const float* __restrict__ img,
                            const float* __restrict__ hraw,
                            const float* __restrict__ b1,
                            const float* __restrict__ w2,
                            const float* __restrict__ b2,
                            float* __restrict__ out) {
    int b = blockIdx.y, r = blockIdx.x, c = threadIdx.x;
    float av = b2[0], bv = b2[1];
#pragma unroll
    for (int l = 0; l < LAT; l++) {
        float h = hraw[b * LAT + l] + b1[l];
        h = h > 0.0f ? h : 0.0f;
        av += h * w2[l * 2 + 0];
        bv += h * w2[l * 2 + 1];
    }
    const float g   = 0.6065306597126334f;   // exp(-0.5)
    const float inv = 1.0f / (1.0f + 2.0f * g);
    const float* I = img + (size_t)b * XS2;
    float up  = (r > 0)      ? I[(r - 1) * XS + c] : 0.0f;
    float mid =                I[r * XS + c];
    float dn  = (r < XS - 1) ? I[(r + 1) * XS + c] : 0.0f;
    float v = (g * (up + dn) + mid) * inv;
    __shared__ float row[XS + 2];
    row[c + 1] = v;
    if (c == 0) { row[0] = 0.0f; row[XS + 1] = 0.0f; }
    __syncthreads();
    float hh = (g * (row[c] + row[c + 2]) + v) * inv;
    out[(size_t)b * XS2 + (size_t)r * XS + c] = av * hh + bv;
}

extern "C" void kernel_launch(void* const* d_in, const int* in_sizes, int n_in,
                              void* d_out, int out_size, void* d_ws, size_t ws_size,
                              hipStream_t stream) {
    const float* flow   = (const float*)d_in[0];
    const float* x      = (const float*)d_in[1];
    const float* values = (const float*)d_in[2];
    const float* rot    = (const float*)d_in[3];
    const float* shifts = (const float*)d_in[4];
    const float* w1     = (const float*)d_in[5];
    const float* b1     = (const float*)d_in[6];
    const float* w2     = (const float*)d_in[7];
    const float* b2     = (const float*)d_in[8];
    const int*   inds   = (const int*)d_in[9];

    int N = in_sizes[2];          // values: (N,)
    int B = in_sizes[4] / 2;      // shifts: (B,2)
    int TI  = B * N;
    int IPB = (TI + P1 - 1) / P1;

    // workspace layout (recs offset is 8B-aligned)
    size_t imgElems = (size_t)B * XS2;
    float*    img     = (float*)d_ws;
    float*    hraw    = img + imgElems;                   // 256 floats reserved
    unsigned* gcursor = (unsigned*)(hraw + 256);          // NBINS (512)
    unsigned long long* recs = (unsigned long long*)(gcursor + NBINS);
    float*    reps    = (float*)(recs + (size_t)NBINS * BINCAP);
    float*    aprons  = reps + (size_t)SPLIT * imgElems;
    size_t needed = (size_t)((char*)(aprons + (size_t)NBINS * SPLIT * XS) - (char*)d_ws);

    bool fast = (B * NG == NBINS) && (ws_size >= needed) && (IPB <= K_MAX * 256);

    hipMemsetAsync(d_ws, 0, imgElems * sizeof(float) + 1024 + NBINS * 4, stream);

    if (fast) {
        place_direct<<<P1, 256, 0, stream>>>(flow, values, inds, rot, shifts,
                                             gcursor, recs, img, N, TI, IPB);
        accum_u64<<<NBINS * SPLIT, 256, 0, stream>>>(recs, gcursor, reps, aprons, B);
        dim3 gc(XS, B);
        combine_kernel<<<gc, 256, 0, stream>>>(img, reps, aprons, B);
    } else {
        dim3 g1((N + 255) / 256, B);
        scatter_kernel<<<g1, 256, 0, stream>>>(flow, values, inds, rot, shifts, img, N);
    }

    mlp_partial<<<XS2 / 256, 256, 0, stream>>>(x, w1, hraw, B);

    dim3 g3(XS, B);
    blur_kernel<<<g3, XS, 0, stream>>>(img, hraw, b1, w2, b2, (float*)d_out);
}